// Round 5
// baseline (20.684 us; speedup 1.0000x reference)
//
#include <hip/hip_runtime.h>

#define AGENT_THRESH 0.5f
#define X_DIS_THRESH 1.5f
#define Y_DIS_THRESH 3.0f
#define DIS2_THRESH  9.0f
#define LOSS_WEIGHT  1.0f
#define FLT_BIG      3.402823466e+38f

constexpr int B = 128, A = 2048, M = 6, T = 12, C = 10;
constexpr int APB = 256;            // agents per block (= threads)
constexpr int CHUNKS = A / APB;     // 8 blocks per batch element
constexpr int NBLK = B * CHUNKS;    // 1024
constexpr int SLOTS = T * 2;        // 24
constexpr int GRP = 10;             // reducer threads per slot (240 active)

// d_ws layout
//   [0)                blockmins: NBLK*SLOTS floats (96 KB)
//   [98304)            partial:   B floats
//   [98304+512)        counter:   1 uint
constexpr size_t WS_PARTIAL_OFF = (size_t)NBLK * SLOTS;          // in floats
constexpr size_t WS_COUNTER_OFF = WS_PARTIAL_OFF + 128;          // in floats

// Kernel 1: per-(b,chunk) block computes 24-slot (t,coord) min over its 256
// agents. Register mins (branchless), LDS transpose-reduce, no atomics.
__global__ __launch_bounds__(APB) void pcl_main_kernel(
    const float* __restrict__ ego,          // [B,T,2]
    const float* __restrict__ agent_preds,  // [B,A,2]
    const float* __restrict__ afp,          // [B,A,M,T,2]
    const float* __restrict__ scores,       // [B,A,C]
    const float* __restrict__ cls,          // [B,A,M]
    float* __restrict__ blockmins,          // [NBLK, 24]
    unsigned int* __restrict__ counter)
{
    const int b     = blockIdx.x / CHUNKS;
    const int chunk = blockIdx.x % CHUNKS;
    const int tid   = threadIdx.x;
    const int a     = chunk * APB + tid;

    if (blockIdx.x == 0 && tid == 0) *counter = 0;  // reset for kernel2 (every call)

    __shared__ float egoraw[SLOTS];
    __shared__ float predx[T], predy[T];
    __shared__ float sred[APB][25];
    __shared__ float spart[SLOTS * GRP];

    const size_t ba = (size_t)b * A + a;

    // --- issue all independent global loads up front ----------------------
    const float2* sp2 = (const float2*)(scores + ba * C);
    float2 s0 = sp2[0], s1 = sp2[1], s2 = sp2[2], s3 = sp2[3], s4 = sp2[4];
    const float2* cp2 = (const float2*)(cls + ba * M);
    float2 c0 = cp2[0], c1 = cp2[1], c2 = cp2[2];
    const float2 apxy = ((const float2*)agent_preds)[ba];

    if (tid < SLOTS) egoraw[tid] = ego[(size_t)b * SLOTS + tid];
    __syncthreads();
    if (tid < SLOTS) {
        const int coord = (tid >= T) ? 1 : 0;
        const int tt    = tid - T * coord;
        float s = 0.f;
        for (int i = 0; i <= tt; ++i) s += egoraw[2 * i + coord];
        if (coord) predy[tt] = s; else predx[tt] = s;
    }
    __syncthreads();

    // --- score argmax / validity ------------------------------------------
    float sv[C] = {s0.x, s0.y, s1.x, s1.y, s2.x, s2.y, s3.x, s3.y, s4.x, s4.y};
    float ms = sv[0];
    int   mi = 0;
    #pragma unroll
    for (int c = 1; c < C; ++c)
        if (sv[c] > ms) { ms = sv[c]; mi = c; }
    const bool valid = (ms >= AGENT_THRESH) && (mi <= 4);

    float p[SLOTS];
    #pragma unroll
    for (int k = 0; k < SLOTS; ++k) p[k] = FLT_BIG;

    if (valid) {
        float cv[M] = {c0.x, c0.y, c1.x, c1.y, c2.x, c2.y};
        float mc = cv[0];
        int   mm = 0;
        #pragma unroll
        for (int m = 1; m < M; ++m)
            if (cv[m] > mc) { mc = cv[m]; mm = m; }

        const float4* fp = (const float4*)(afp + (ba * M + mm) * (size_t)SLOTS);
        float4 f0 = fp[0], f1 = fp[1], f2 = fp[2], f3 = fp[3], f4 = fp[4], f5 = fp[5];
        float dxv[SLOTS];
        dxv[0]=f0.x; dxv[1]=f0.y; dxv[2]=f0.z; dxv[3]=f0.w;
        dxv[4]=f1.x; dxv[5]=f1.y; dxv[6]=f1.z; dxv[7]=f1.w;
        dxv[8]=f2.x; dxv[9]=f2.y; dxv[10]=f2.z; dxv[11]=f2.w;
        dxv[12]=f3.x; dxv[13]=f3.y; dxv[14]=f3.z; dxv[15]=f3.w;
        dxv[16]=f4.x; dxv[17]=f4.y; dxv[18]=f4.z; dxv[19]=f4.w;
        dxv[20]=f5.x; dxv[21]=f5.y; dxv[22]=f5.z; dxv[23]=f5.w;

        float csx = 0.f, csy = 0.f;
        #pragma unroll
        for (int t = 0; t < T; ++t) {
            csx += dxv[2 * t + 0];
            csy += dxv[2 * t + 1];
            const float dx = predx[t] - (apxy.x + csx);
            const float dy = predy[t] - (apxy.y + csy);
            const bool hit = (dx * dx + dy * dy <= DIS2_THRESH);
            p[2 * t + 0] = fminf(p[2 * t + 0], hit ? fabsf(dx) : FLT_BIG);
            p[2 * t + 1] = fminf(p[2 * t + 1], hit ? fabsf(dy) : FLT_BIG);
        }
    }

    // --- transpose-reduce --------------------------------------------------
    #pragma unroll
    for (int k = 0; k < SLOTS; ++k) sred[tid][k] = p[k];
    __syncthreads();

    if (tid < SLOTS * GRP) {
        const int s = tid % SLOTS;
        const int g = tid / SLOTS;
        float pm = FLT_BIG;
        for (int r = g; r < APB; r += GRP) pm = fminf(pm, sred[r][s]);
        spart[tid] = pm;
    }
    __syncthreads();

    if (tid < SLOTS) {
        float m = spart[tid];
        #pragma unroll
        for (int g = 1; g < GRP; ++g) m = fminf(m, spart[g * SLOTS + tid]);
        blockmins[(size_t)blockIdx.x * SLOTS + tid] = m;
    }
}

// Kernel 2: 128 blocks (one per b). Block b reduces its 8 chunk-rows, applies
// hinge, sums 24 slots -> partial[b]. Last finishing block (device-scope
// atomic counter) sums the 128 partials in fixed order and writes out.
__global__ __launch_bounds__(192) void pcl_finalize_kernel(
    const float* __restrict__ blockmins,    // [NBLK, 24]
    float* __restrict__ partial,            // [B]
    unsigned int* __restrict__ counter,
    float* __restrict__ out)
{
    const int b   = blockIdx.x;
    const int tid = threadIdx.x;            // 192 = 8 chunks x 24 slots

    __shared__ float sv[CHUNKS * SLOTS];
    __shared__ float ssum[SLOTS];
    __shared__ bool  is_last;

    // coalesced read of this b's 8x24 table (768 B)
    sv[tid] = blockmins[(size_t)b * CHUNKS * SLOTS + tid];
    __syncthreads();

    if (tid < SLOTS) {
        float m = sv[tid];
        #pragma unroll
        for (int c = 1; c < CHUNKS; ++c) m = fminf(m, sv[c * SLOTS + tid]);
        const float thr = (tid & 1) ? Y_DIS_THRESH : X_DIS_THRESH;
        ssum[tid] = (m > thr) ? 0.f : (thr - m);
    }
    __syncthreads();

    if (tid == 0) {
        float s = 0.f;
        #pragma unroll
        for (int k = 0; k < SLOTS; ++k) s += ssum[k];
        partial[b] = s;
        __threadfence();                           // publish partial[b]
        unsigned int prev = atomicAdd(counter, 1u);
        is_last = (prev == (unsigned int)(B - 1));
    }
    __syncthreads();

    if (is_last) {
        __threadfence();                           // acquire all partials
        if (tid < 64) {
            volatile const float* vp = partial;
            float s = vp[tid] + vp[tid + 64];      // fixed pairing
            #pragma unroll
            for (int off = 32; off > 0; off >>= 1)
                s += __shfl_down(s, off, 64);      // fixed tree -> deterministic
            if (tid == 0)
                out[0] = LOSS_WEIGHT * s / (float)(B * SLOTS);
        }
    }
}

extern "C" void kernel_launch(void* const* d_in, const int* in_sizes, int n_in,
                              void* d_out, int out_size, void* d_ws, size_t ws_size,
                              hipStream_t stream) {
    const float* ego         = (const float*)d_in[0];  // [B,T,2]
    const float* agent_preds = (const float*)d_in[1];  // [B,A,2]
    const float* afp         = (const float*)d_in[2];  // [B,A,M,T,2]
    const float* scores      = (const float*)d_in[3];  // [B,A,C]
    const float* cls         = (const float*)d_in[4];  // [B,A,M]
    float* out               = (float*)d_out;

    float* blockmins         = (float*)d_ws;                    // 96 KB
    float* partial           = (float*)d_ws + WS_PARTIAL_OFF;   // 128 floats
    unsigned int* counter    = (unsigned int*)((float*)d_ws + WS_COUNTER_OFF);

    pcl_main_kernel<<<NBLK, APB, 0, stream>>>(
        ego, agent_preds, afp, scores, cls, blockmins, counter);
    pcl_finalize_kernel<<<B, 192, 0, stream>>>(blockmins, partial, counter, out);
}